// Round 6
// baseline (455.749 us; speedup 1.0000x reference)
//
#include <hip/hip_runtime.h>

#define NN 50000
#define NP 50176      // 392 row-tiles of 128; 392 % 8 == 0 for XCD grouping
#define NE 800000
#define CH 512
#define NB 196        // ceil(50000/256) scan blocks
#define PB_TRANS 2048 // 2 * CH*CH/256
#define PB_DEG 782    // ceil(NE/4/256)
#define PB_PERM 6     // 3*512/256 permuted-vector blocks
#define SMB 49        // softmax partial blocks (49*1024 >= 50000)
#define GB1 (4 * (NP / 128))          // 1568 gemm blocks (128x128 tiles)
#define BKB ((NE / 2 + 255) / 256)    // 1563 bucket blocks

typedef __bf16 bf16x8 __attribute__((ext_vector_type(8)));
typedef float f32x4 __attribute__((ext_vector_type(4)));
typedef float f32x2 __attribute__((ext_vector_type(2)));
typedef unsigned short u16x8 __attribute__((ext_vector_type(8)));

static __device__ __forceinline__ unsigned short f2b(float f){
  unsigned u = __builtin_bit_cast(unsigned, f);
  u = (u + 0x7fffu + ((u >> 16) & 1u)) >> 16;   // RNE f32 -> bf16
  return (unsigned short)u;
}
static __device__ __forceinline__ float b2f(unsigned short h){
  unsigned u = ((unsigned)h) << 16;
  return __builtin_bit_cast(float, u);
}
static __device__ __forceinline__ float rdlane_f(float v, int l){
  return __builtin_bit_cast(float, __builtin_amdgcn_readlane(__builtin_bit_cast(int, v), l));
}
// pack two f32 -> two bf16 (round-half-up) in one dword: 2 adds + 1 v_perm
static __device__ __forceinline__ unsigned pack2(float f0, float f1){
  unsigned u0 = __builtin_bit_cast(unsigned, f0) + 0x8000u;
  unsigned u1 = __builtin_bit_cast(unsigned, f1) + 0x8000u;
  return __builtin_amdgcn_perm(u1, u0, 0x07060302u);  // [u1.hi16 | u0.hi16]
}
// physical column p -> logical channel (epilogue permutation, within 64-blocks)
// epilogue stores logical (j*16 + l15) at physical (l15*4 + j), j<4, l15<16
static __device__ __forceinline__ int lam(int p){
  return (p & ~63) | (((p & 3) << 4) + ((p & 63) >> 2));
}

// ---- prep: W1t | W2t (k-permuted) | deg hist (+edge rank) | permuted vecs ----
__global__ void k_prep(const float* __restrict__ W1, const float* __restrict__ W2,
                       unsigned short* __restrict__ W1t, unsigned short* __restrict__ W2t,
                       const int* __restrict__ ei, int* __restrict__ deg,
                       int* __restrict__ rank,
                       const float* __restrict__ b1, const float* __restrict__ b2,
                       const float* __restrict__ Wo, float* __restrict__ b1p,
                       float* __restrict__ b2p, float* __restrict__ Wop){
  const int b = blockIdx.x, t = threadIdx.x;
  if (b < PB_TRANS){
    int idx = (b & 1023) * 256 + t;
    int n = idx >> 9, p = idx & (CH - 1);
    if (b < 1024)
      W1t[n * CH + p] = f2b(W1[p * CH + n]);            // logical k
    else
      W2t[n * CH + p] = f2b(W2[lam(p) * CH + n]);       // k permuted to match B0 layout
  } else if (b < PB_TRANS + PB_DEG){
    int e4 = ((b - PB_TRANS) * 256 + t) * 4;
    if (e4 < NE){
      int4 d = *(const int4*)(ei + NE + e4);
      int4 r;
      r.x = atomicAdd(&deg[d.x], 1);
      r.y = atomicAdd(&deg[d.y], 1);
      r.z = atomicAdd(&deg[d.z], 1);
      r.w = atomicAdd(&deg[d.w], 1);
      *(int4*)(rank + e4) = r;   // within-node rank; makes bucket atomic-free
    }
  } else {
    int idx = (b - PB_TRANS - PB_DEG) * 256 + t;  // [0,1536)
    int which = idx >> 9, p = idx & (CH - 1);
    int l = lam(p);
    if (which == 0) b1p[p] = b1[l];
    else if (which == 1) b2p[p] = b2[l];
    else Wop[p] = Wo[l];
  }
}

// ---- hierarchical scan: block sums -> scan -> scatter ----
__global__ void k_blocksum(const int* __restrict__ deg, int* __restrict__ bsum){
  __shared__ int sh[4];
  const int t = threadIdx.x;
  int i = blockIdx.x * 256 + t;
  int v = (i < NN) ? deg[i] : 0;
  #pragma unroll
  for (int off = 32; off > 0; off >>= 1) v += __shfl_down(v, off, 64);
  if ((t & 63) == 0) sh[t >> 6] = v;
  __syncthreads();
  if (t == 0) bsum[blockIdx.x] = sh[0] + sh[1] + sh[2] + sh[3];
}

__global__ void k_scanoff(const int* __restrict__ bsum, int* __restrict__ boff,
                          int* __restrict__ row_ptr){
  __shared__ int sh[256];
  const int t = threadIdx.x;
  int v = (t < NB) ? bsum[t] : 0;
  sh[t] = v; __syncthreads();
  for (int d = 1; d < 256; d <<= 1){
    int add = (t >= d) ? sh[t - d] : 0;
    __syncthreads();
    sh[t] += add;
    __syncthreads();
  }
  if (t < NB) boff[t] = sh[t] - v;
  if (t == 255) row_ptr[NN] = sh[255];
}

__global__ void k_scatter(const int* __restrict__ deg, const int* __restrict__ boff,
                          int* __restrict__ row_ptr, float* __restrict__ dinv){
  __shared__ int sh[256];
  const int t = threadIdx.x;
  int i = blockIdx.x * 256 + t;
  int d = (i < NN) ? deg[i] : 0;
  sh[t] = d; __syncthreads();
  for (int dd = 1; dd < 256; dd <<= 1){
    int add = (t >= dd) ? sh[t - dd] : 0;
    __syncthreads();
    sh[t] += add;
    __syncthreads();
  }
  if (i < NN){
    row_ptr[i] = sh[t] - d + boff[blockIdx.x];
    dinv[i] = rsqrtf((float)d + 1.0f);   // +1 self-loop
  }
}

// ---- GEMM body: 128x128 tile, XCD swizzle, 2-deep counted-vmcnt pipeline ----
// T3/T4 minimum recipe: 3 LDS buffers; stage tile it+2 during it; raw
// s_barrier preceded by s_waitcnt vmcnt(N) (N = loads of tile it+1 still in
// flight: 4 non-CVT, 2 CVT), vmcnt(0) only on the last iteration. Buffer
// reuse safe: tile it's ds_reads complete before the top-of-(it+1) barrier,
// and tile it+3 is staged after it (during it+1).
template<bool CVT>
static __device__ __forceinline__ void gemm_body(
    const int bx, const int t,
    const void* __restrict__ Av, const unsigned short* __restrict__ Bt,
    unsigned char* __restrict__ C,
    unsigned short (&As)[3][4096], unsigned short (&Bs)[3][4096]){
  const int wave = t >> 6, lane = t & 63;
  const int quad = lane >> 4, l15 = lane & 15;
  const int mw = (wave & 1) * 64;
  const int nw = (wave >> 1) * 64;
  const int g = bx >> 5, rem = bx & 31;
  const int rt = g * 8 + (rem & 7);
  const int rowBase = rt * 128;
  const int nBase = (rem >> 3) * 128;

  const int lr = lane >> 2;              // 16-row async chunks
  const int lc = (lane & 3) * 8;
  const int lr8 = lane >> 3;             // 8-row f32 chunks (CVT path)
  const int lc8 = lane & 7;
  const unsigned short* Bg0 = Bt + (size_t)(nBase + wave * 32 + lr) * CH + lc;
  const int boff = wave * 1024;          // 32 rows * 32 k per wave
  const float* X = (const float*)Av;
  const unsigned short* Ag0 = (const unsigned short*)Av;
  if (!CVT) Ag0 += (size_t)(rowBase + wave * 32 + lr) * CH + lc;
  const int aoff = wave * 1024;

  int arow[4]; size_t asrc[4];
  if (CVT){
    #pragma unroll
    for (int q=0;q<4;q++){
      arow[q] = wave * 32 + q * 8 + lr8;               // local row in tile
      int gr = rowBase + arow[q];
      if (gr >= NN) gr = 0;                            // clamp: pad rows unread
      asrc[q] = (size_t)gr * CH + lc8 * 4;
    }
  }

  f32x4 acc[4][4];
  #pragma unroll
  for (int i=0;i<4;i++)
    #pragma unroll
    for (int j=0;j<4;j++) acc[i][j] = 0;

  // ---- prologue: stage tiles 0 and 1 ----
  if (CVT){
    float4 a0[4], a1[4];
    #pragma unroll
    for (int q=0;q<4;q++) a0[q] = *(const float4*)(X + asrc[q]);
    #pragma unroll
    for (int q=0;q<2;q++)
      __builtin_amdgcn_global_load_lds(
        (const __attribute__((address_space(1))) void*)(Bg0 + (size_t)q*16*CH),
        (__attribute__((address_space(3))) void*)(&Bs[0][boff + q*512]), 16, 0, 0);
    #pragma unroll
    for (int q=0;q<4;q++) a1[q] = *(const float4*)(X + asrc[q] + 32);
    #pragma unroll
    for (int q=0;q<2;q++)
      __builtin_amdgcn_global_load_lds(
        (const __attribute__((address_space(1))) void*)(Bg0 + (size_t)q*16*CH + 32),
        (__attribute__((address_space(3))) void*)(&Bs[1][boff + q*512]), 16, 0, 0);
    #pragma unroll
    for (int q=0;q<4;q++){
      uint2 pk; pk.x = pack2(a0[q].x, a0[q].y); pk.y = pack2(a0[q].z, a0[q].w);
      *(uint2*)&As[0][arow[q] * 32 + lc8 * 4] = pk;
    }
    #pragma unroll
    for (int q=0;q<4;q++){
      uint2 pk; pk.x = pack2(a1[q].x, a1[q].y); pk.y = pack2(a1[q].z, a1[q].w);
      *(uint2*)&As[1][arow[q] * 32 + lc8 * 4] = pk;
    }
  } else {
    #pragma unroll
    for (int tt=0;tt<2;tt++){
      #pragma unroll
      for (int q=0;q<2;q++)
        __builtin_amdgcn_global_load_lds(
          (const __attribute__((address_space(1))) void*)(Ag0 + (size_t)q*16*CH + tt*32),
          (__attribute__((address_space(3))) void*)(&As[tt][aoff + q*512]), 16, 0, 0);
      #pragma unroll
      for (int q=0;q<2;q++)
        __builtin_amdgcn_global_load_lds(
          (const __attribute__((address_space(1))) void*)(Bg0 + (size_t)q*16*CH + tt*32),
          (__attribute__((address_space(3))) void*)(&Bs[tt][boff + q*512]), 16, 0, 0);
    }
  }

  int cur = 0;
  float4 apre[4];
  for (int it = 0; it < 16; it++){
    const int b2 = cur ? cur - 1 : 2;    // (cur+2) % 3
    // counted drain: tile `it` must be resident; tile it+1's loads may fly
    if (it < 15){
      if (CVT) asm volatile("s_waitcnt vmcnt(2) lgkmcnt(0)" ::: "memory");
      else     asm volatile("s_waitcnt vmcnt(4) lgkmcnt(0)" ::: "memory");
    } else {
      asm volatile("s_waitcnt vmcnt(0) lgkmcnt(0)" ::: "memory");
    }
    __builtin_amdgcn_sched_barrier(0);
    __builtin_amdgcn_s_barrier();
    __builtin_amdgcn_sched_barrier(0);

    if (it < 14){
      const int kb = (it + 2) * 32;
      if (CVT){
        #pragma unroll
        for (int q=0;q<4;q++) apre[q] = *(const float4*)(X + asrc[q] + kb);
      } else {
        #pragma unroll
        for (int q=0;q<2;q++)
          __builtin_amdgcn_global_load_lds(
            (const __attribute__((address_space(1))) void*)(Ag0 + (size_t)q*16*CH + kb),
            (__attribute__((address_space(3))) void*)(&As[b2][aoff + q*512]), 16, 0, 0);
      }
      #pragma unroll
      for (int q=0;q<2;q++)
        __builtin_amdgcn_global_load_lds(
          (const __attribute__((address_space(1))) void*)(Bg0 + (size_t)q*16*CH + kb),
          (__attribute__((address_space(3))) void*)(&Bs[b2][boff + q*512]), 16, 0, 0);
    }

    bf16x8 af[4], bfr[4];
    #pragma unroll
    for (int i=0;i<4;i++)
      af[i] = __builtin_bit_cast(bf16x8,
              *(const u16x8*)&As[cur][(mw + i*16 + l15) * 32 + quad * 8]);
    #pragma unroll
    for (int j=0;j<4;j++)
      bfr[j] = __builtin_bit_cast(bf16x8,
              *(const u16x8*)&Bs[cur][(nw + j*16 + l15) * 32 + quad * 8]);
    #pragma unroll
    for (int i=0;i<4;i++)
      #pragma unroll
      for (int j=0;j<4;j++)
        acc[i][j] = __builtin_amdgcn_mfma_f32_16x16x32_bf16(af[i], bfr[j], acc[i][j], 0, 0, 0);

    if (CVT && it < 14){   // convert in the MFMA shadow, write tile it+2
      #pragma unroll
      for (int q=0;q<4;q++){
        uint2 pk; pk.x = pack2(apre[q].x, apre[q].y); pk.y = pack2(apre[q].z, apre[q].w);
        *(uint2*)&As[b2][arow[q] * 32 + lc8 * 4] = pk;
      }
    }
    cur = (cur == 2) ? 0 : cur + 1;
  }

  // permuted epilogue: lane packs its 4 j-values of one row -> 4B fp8 store
  #pragma unroll
  for (int i=0;i<4;i++){
    #pragma unroll
    for (int r=0;r<4;r++){
      int row = rowBase + mw + i*16 + quad*4 + r;
      int w0 = 0;
      w0 = __builtin_amdgcn_cvt_pk_fp8_f32(acc[i][0][r], acc[i][1][r], w0, false);
      w0 = __builtin_amdgcn_cvt_pk_fp8_f32(acc[i][2][r], acc[i][3][r], w0, true);
      *(unsigned*)(C + (size_t)row * CH + nBase + nw + l15*4) = (unsigned)w0;
    }
  }
}

// ---- gemm1: CVT (f32 x -> bf16 LDS), fp8 C ----
__launch_bounds__(256, 3)
__global__ void k_gemm1(const float* __restrict__ x, const unsigned short* __restrict__ W1t,
                        unsigned char* __restrict__ C){
  __shared__ __align__(16) unsigned short As[3][4096];
  __shared__ __align__(16) unsigned short Bs[3][4096];
  gemm_body<true>(blockIdx.x, threadIdx.x, x, W1t, C, As, Bs);
}

// ---- bucket: atomic-free CSR scatter (separate kernel) ----
__global__ void k_bucket(const int* __restrict__ ei, const int* __restrict__ row_ptr,
                         const int* __restrict__ rank, int* __restrict__ csr_src){
  int e2 = (blockIdx.x * 256 + threadIdx.x) * 2;
  if (e2 < NE){
    int2 src = *(const int2*)(ei + e2);
    int2 dst = *(const int2*)(ei + NE + e2);
    int2 rk  = *(const int2*)(rank + e2);
    csr_src[row_ptr[dst.x] + rk.x] = src.x;
    csr_src[row_ptr[dst.y] + rk.y] = src.y;
  }
}

// ---- gemm2: bf16 A (B0), LDS dbuf, fp8 C ----
__launch_bounds__(256, 3)
__global__ void k_gemm2(const unsigned short* __restrict__ A,
                        const unsigned short* __restrict__ Bt,
                        unsigned char* __restrict__ C){
  __shared__ __align__(16) unsigned short As[3][4096];
  __shared__ __align__(16) unsigned short Bs[3][4096];
  gemm_body<false>(blockIdx.x, threadIdx.x, A, Bt, C, As, Bs);
}

// ---- aggregation: relu(di*sum + di^2*self + b); optional fused head ----
// h table is FP8 e4m3 (512 B/row): halves the random-gather fetch volume.
template<bool HEAD>
__launch_bounds__(256)
__global__ void k_agg(const unsigned char* __restrict__ h, const int* __restrict__ row_ptr,
                      const int* __restrict__ csr_src, const float* __restrict__ dinv,
                      const float* __restrict__ bias, unsigned short* __restrict__ out,
                      const float* __restrict__ Wo, const float* __restrict__ bo,
                      float* __restrict__ logits){
  const int node = blockIdx.x * 4 + (threadIdx.x >> 6);
  const int lane = threadIdx.x & 63;
  float acc[8];
  #pragma unroll
  for (int k=0;k<8;k++) acc[k] = 0.f;
  const int rp = row_ptr[node], re = row_ptr[node + 1];
  for (int base = rp; base < re; base += 64){
    int cnt = re - base; if (cnt > 64) cnt = 64;
    int s = 0; float w = 0.f;
    if (base + lane < re){ s = csr_src[base + lane]; w = dinv[s]; }
    int j = 0;
    for (; j + 8 <= cnt; j += 8){
      int ss[8]; float ww[8]; uint2 hv[8];
      #pragma unroll
      for (int u=0;u<8;u++){
        ss[u] = __builtin_amdgcn_readlane(s, j + u);
        ww[u] = rdlane_f(w, j + u);
      }
      #pragma unroll
      for (int u=0;u<8;u++)
        hv[u] = *(const uint2*)(h + (size_t)ss[u] * CH + lane * 8);
      #pragma unroll
      for (int u=0;u<8;u++){
        f32x2 p0 = __builtin_amdgcn_cvt_pk_f32_fp8((int)hv[u].x, false);
        f32x2 p1 = __builtin_amdgcn_cvt_pk_f32_fp8((int)hv[u].x, true);
        f32x2 p2 = __builtin_amdgcn_cvt_pk_f32_fp8((int)hv[u].y, false);
        f32x2 p3 = __builtin_amdgcn_cvt_pk_f32_fp8((int)hv[u].y, true);
        acc[0] += ww[u] * p0.x; acc[1] += ww[u] * p0.y;
        acc[2] += ww[u] * p1.x; acc[3] += ww[u] * p1.y;
        acc[4] += ww[u] * p2.x; acc[5] += ww[u] * p2.y;
        acc[6] += ww[u] * p3.x; acc[7] += ww[u] * p3.y;
      }
    }
    for (; j < cnt; j++){
      int ss = __builtin_amdgcn_readlane(s, j);
      float ww = rdlane_f(w, j);
      uint2 hv = *(const uint2*)(h + (size_t)ss * CH + lane * 8);
      f32x2 p0 = __builtin_amdgcn_cvt_pk_f32_fp8((int)hv.x, false);
      f32x2 p1 = __builtin_amdgcn_cvt_pk_f32_fp8((int)hv.x, true);
      f32x2 p2 = __builtin_amdgcn_cvt_pk_f32_fp8((int)hv.y, false);
      f32x2 p3 = __builtin_amdgcn_cvt_pk_f32_fp8((int)hv.y, true);
      acc[0] += ww * p0.x; acc[1] += ww * p0.y;
      acc[2] += ww * p1.x; acc[3] += ww * p1.y;
      acc[4] += ww * p2.x; acc[5] += ww * p2.y;
      acc[6] += ww * p3.x; acc[7] += ww * p3.y;
    }
  }
  const float di = dinv[node];
  uint2 hsv = *(const uint2*)(h + (size_t)node * CH + lane * 8);
  f32x2 s0 = __builtin_amdgcn_cvt_pk_f32_fp8((int)hsv.x, false);
  f32x2 s1 = __builtin_amdgcn_cvt_pk_f32_fp8((int)hsv.x, true);
  f32x2 s2 = __builtin_amdgcn_cvt_pk_f32_fp8((int)hsv.y, false);
  f32x2 s3 = __builtin_amdgcn_cvt_pk_f32_fp8((int)hsv.y, true);
  float hsf[8] = {s0.x, s0.y, s1.x, s1.y, s2.x, s2.y, s3.x, s3.y};
  const float4* bp = (const float4*)(bias + lane * 8);
  float4 bv0 = bp[0], bv1 = bp[1];
  float bb[8] = {bv0.x,bv0.y,bv0.z,bv0.w,bv1.x,bv1.y,bv1.z,bv1.w};
  if (HEAD){
    const float4* wp = (const float4*)(Wo + lane * 8);
    float4 w0 = wp[0], w1 = wp[1];
    float wv[8] = {w0.x,w0.y,w0.z,w0.w,w1.x,w1.y,w1.z,w1.w};
    float v = 0.f;
    #pragma unroll
    for (int k=0;k<8;k++){
      float r = fmaxf(di * acc[k] + di * di * hsf[k] + bb[k], 0.f);
      v += r * wv[k];
    }
    #pragma unroll
    for (int off = 32; off > 0; off >>= 1) v += __shfl_down(v, off, 64);
    if (lane == 0) logits[node] = v + bo[0];
  } else {
    u16x8 o;
    #pragma unroll
    for (int k=0;k<8;k++){
      float r = fmaxf(di * acc[k] + di * di * hsf[k] + bb[k], 0.f);
      o[k] = f2b(r);
    }
    *(u16x8*)(out + (size_t)node * CH + lane * 8) = o;
  }
}

// ---- softmax: 49-block partial (m_b, s_b); final combine folded into write ----
__global__ void k_smpart(const float* __restrict__ logits, float* __restrict__ pm,
                         float* __restrict__ ps){
  __shared__ float shm[16], shs[16];
  const int t = threadIdx.x;
  const int i = blockIdx.x * 1024 + t;
  float v = (i < NN) ? logits[i] : -3.4e38f;
  float m = v;
  #pragma unroll
  for (int off = 32; off > 0; off >>= 1) m = fmaxf(m, __shfl_down(m, off, 64));
  if ((t & 63) == 0) shm[t >> 6] = m;
  __syncthreads();
  if (t < 64){
    float mm = (t < 16) ? shm[t] : -3.4e38f;
    #pragma unroll
    for (int off = 8; off > 0; off >>= 1) mm = fmaxf(mm, __shfl_down(mm, off, 64));
    if (t == 0) shm[0] = mm;
  }
  __syncthreads();
  const float bm = shm[0];
  float s = (i < NN) ? expf(v - bm) : 0.f;
  #pragma unroll
  for (int off = 32; off > 0; off >>= 1) s += __shfl_down(s, off, 64);
  if ((t & 63) == 0) shs[t >> 6] = s;
  __syncthreads();
  if (t < 64){
    float sss = (t < 16) ? shs[t] : 0.f;
    #pragma unroll
    for (int off = 8; off > 0; off >>= 1) sss += __shfl_down(sss, off, 64);
    if (t == 0){ pm[blockIdx.x] = bm; ps[blockIdx.x] = sss; }
  }
}

__global__ void k_smwrite(const float* __restrict__ logits, const float* __restrict__ pm,
                          const float* __restrict__ ps, float* __restrict__ out){
  __shared__ float shMS[2];
  const int t = threadIdx.x;
  if (t < 64){
    float m = (t < SMB) ? pm[t] : -3.4e38f;
    float M = m;
    #pragma unroll
    for (int off = 32; off > 0; off >>= 1) M = fmaxf(M, __shfl_down(M, off, 64));
    M = rdlane_f(M, 0);
    float s = (t < SMB) ? ps[t] * expf(m - M) : 0.f;
    #pragma unroll
    for (int off = 32; off > 0; off >>= 1) s += __shfl_down(s, off, 64);
    if (t == 0){ shMS[0] = M; shMS[1] = s; }
  }
  __syncthreads();
  int i = blockIdx.x * blockDim.x + t;
  if (i < NN) out[i] = expf(logits[i] - shMS[0]) / shMS[1];
}

extern "C" void kernel_launch(void* const* d_in, const int* in_sizes, int n_in,
                              void* d_out, int out_size, void* d_ws, size_t ws_size,
                              hipStream_t stream){
  const float* x  = (const float*)d_in[0];
  const int*   ei = (const int*)d_in[1];
  const float* W1 = (const float*)d_in[2];
  const float* b1 = (const float*)d_in[3];
  const float* W2 = (const float*)d_in[4];
  const float* b2 = (const float*)d_in[5];
  const float* Wo = (const float*)d_in[6];
  const float* bo = (const float*)d_in[7];
  float* out = (float*)d_out;

  char* ws = (char*)d_ws;
  size_t off = 0;
  auto alloc = [&](size_t bytes) -> void* {
    void* p = ws + off;
    off = (off + bytes + 255) & ~(size_t)255;
    return p;
  };
  unsigned short* B0  = (unsigned short*)alloc((size_t)NP * CH * 2);  // bf16 (gemm2 A input)
  unsigned char*  B1  = (unsigned char*)alloc((size_t)NP * CH);      // fp8 gather table
  unsigned short* W1t = (unsigned short*)alloc((size_t)CH * CH * 2);
  unsigned short* W2t = (unsigned short*)alloc((size_t)CH * CH * 2);
  int*   deg     = (int*)alloc((size_t)NN * 4);
  float* dinv    = (float*)alloc((size_t)NN * 4);
  int*   row_ptr = (int*)alloc((size_t)(NN + 1) * 4);
  int*   rank    = (int*)alloc((size_t)NE * 4);
  int*   csr     = (int*)alloc((size_t)NE * 4);
  float* logits  = (float*)alloc((size_t)NN * 4);
  int*   bsum    = (int*)alloc((size_t)NB * 4);
  int*   boff    = (int*)alloc((size_t)NB * 4);
  float* pm      = (float*)alloc((size_t)SMB * 4);
  float* ps      = (float*)alloc((size_t)SMB * 4);
  float* b1p     = (float*)alloc((size_t)CH * 4);
  float* b2p     = (float*)alloc((size_t)CH * 4);
  float* Wop     = (float*)alloc((size_t)CH * 4);

  hipMemsetAsync(deg, 0, (size_t)NN * 4, stream);
  k_prep<<<PB_TRANS + PB_DEG + PB_PERM, 256, 0, stream>>>(
      W1, W2, W1t, W2t, ei, deg, rank, b1, b2, Wo, b1p, b2p, Wop);
  k_blocksum<<<NB, 256, 0, stream>>>(deg, bsum);
  k_scanoff<<<1, 256, 0, stream>>>(bsum, boff, row_ptr);
  k_scatter<<<NB, 256, 0, stream>>>(deg, boff, row_ptr, dinv);

  k_bucket<<<BKB, 256, 0, stream>>>(ei, row_ptr, rank, csr);
  k_gemm1<<<GB1, 256, 0, stream>>>(x, W1t, B1);
  k_agg<false><<<NN / 4, 256, 0, stream>>>(B1, row_ptr, csr, dinv, b1p, B0,
                                           Wop, bo, logits);
  k_gemm2<<<GB1, 256, 0, stream>>>(B0, W2t, B1);
  k_agg<true><<<NN / 4, 256, 0, stream>>>(B1, row_ptr, csr, dinv, b2p, B0,
                                          Wop, bo, logits);

  k_smpart<<<SMB, 1024, 0, stream>>>(logits, pm, ps);
  k_smwrite<<<NB, 256, 0, stream>>>(logits, pm, ps, out);
}

// Round 7
// 431.531 us; speedup vs baseline: 1.0561x; 1.0561x over previous
//
#include <hip/hip_runtime.h>

#define NN 50000
#define NP 50176      // 392 row-tiles of 128; 392 % 8 == 0 for XCD grouping
#define NE 800000
#define CH 512
#define NB 196        // ceil(50000/256) scan blocks
#define PB_TRANS 2048 // 2 * CH*CH/256
#define PB_DEG 782    // ceil(NE/4/256)
#define PB_PERM 6     // 3*512/256 permuted-vector blocks
#define SMB 49        // softmax partial blocks (49*1024 >= 50000)
#define GB1 (4 * (NP / 128))          // 1568 gemm blocks (128x128 tiles)
#define BKB ((NE / 2 + 255) / 256)    // 1563 bucket blocks

typedef __bf16 bf16x8 __attribute__((ext_vector_type(8)));
typedef float f32x4 __attribute__((ext_vector_type(4)));
typedef float f32x2 __attribute__((ext_vector_type(2)));
typedef unsigned short u16x8 __attribute__((ext_vector_type(8)));

static __device__ __forceinline__ unsigned short f2b(float f){
  unsigned u = __builtin_bit_cast(unsigned, f);
  u = (u + 0x7fffu + ((u >> 16) & 1u)) >> 16;   // RNE f32 -> bf16
  return (unsigned short)u;
}
static __device__ __forceinline__ float b2f(unsigned short h){
  unsigned u = ((unsigned)h) << 16;
  return __builtin_bit_cast(float, u);
}
static __device__ __forceinline__ float rdlane_f(float v, int l){
  return __builtin_bit_cast(float, __builtin_amdgcn_readlane(__builtin_bit_cast(int, v), l));
}
// pack two f32 -> two bf16 (round-half-up) in one dword: 2 adds + 1 v_perm
static __device__ __forceinline__ unsigned pack2(float f0, float f1){
  unsigned u0 = __builtin_bit_cast(unsigned, f0) + 0x8000u;
  unsigned u1 = __builtin_bit_cast(unsigned, f1) + 0x8000u;
  return __builtin_amdgcn_perm(u1, u0, 0x07060302u);  // [u1.hi16 | u0.hi16]
}
// physical column p -> logical channel (epilogue permutation, within 64-blocks)
// epilogue stores logical (j*16 + l15) at physical (l15*4 + j), j<4, l15<16
static __device__ __forceinline__ int lam(int p){
  return (p & ~63) | (((p & 3) << 4) + ((p & 63) >> 2));
}

// ---- prep: W1t | W2t (k-permuted) | deg hist (+edge rank) | permuted vecs ----
__global__ void k_prep(const float* __restrict__ W1, const float* __restrict__ W2,
                       unsigned short* __restrict__ W1t, unsigned short* __restrict__ W2t,
                       const int* __restrict__ ei, int* __restrict__ deg,
                       int* __restrict__ rank,
                       const float* __restrict__ b1, const float* __restrict__ b2,
                       const float* __restrict__ Wo, float* __restrict__ b1p,
                       float* __restrict__ b2p, float* __restrict__ Wop){
  const int b = blockIdx.x, t = threadIdx.x;
  if (b < PB_TRANS){
    int idx = (b & 1023) * 256 + t;
    int n = idx >> 9, p = idx & (CH - 1);
    if (b < 1024)
      W1t[n * CH + p] = f2b(W1[p * CH + n]);            // logical k
    else
      W2t[n * CH + p] = f2b(W2[lam(p) * CH + n]);       // k permuted to match B0 layout
  } else if (b < PB_TRANS + PB_DEG){
    int e4 = ((b - PB_TRANS) * 256 + t) * 4;
    if (e4 < NE){
      int4 d = *(const int4*)(ei + NE + e4);
      int4 r;
      r.x = atomicAdd(&deg[d.x], 1);
      r.y = atomicAdd(&deg[d.y], 1);
      r.z = atomicAdd(&deg[d.z], 1);
      r.w = atomicAdd(&deg[d.w], 1);
      *(int4*)(rank + e4) = r;   // within-node rank; makes bucket atomic-free
    }
  } else {
    int idx = (b - PB_TRANS - PB_DEG) * 256 + t;  // [0,1536)
    int which = idx >> 9, p = idx & (CH - 1);
    int l = lam(p);
    if (which == 0) b1p[p] = b1[l];
    else if (which == 1) b2p[p] = b2[l];
    else Wop[p] = Wo[l];
  }
}

// ---- hierarchical scan: block sums -> scan -> scatter ----
__global__ void k_blocksum(const int* __restrict__ deg, int* __restrict__ bsum){
  __shared__ int sh[4];
  const int t = threadIdx.x;
  int i = blockIdx.x * 256 + t;
  int v = (i < NN) ? deg[i] : 0;
  #pragma unroll
  for (int off = 32; off > 0; off >>= 1) v += __shfl_down(v, off, 64);
  if ((t & 63) == 0) sh[t >> 6] = v;
  __syncthreads();
  if (t == 0) bsum[blockIdx.x] = sh[0] + sh[1] + sh[2] + sh[3];
}

__global__ void k_scanoff(const int* __restrict__ bsum, int* __restrict__ boff,
                          int* __restrict__ row_ptr){
  __shared__ int sh[256];
  const int t = threadIdx.x;
  int v = (t < NB) ? bsum[t] : 0;
  sh[t] = v; __syncthreads();
  for (int d = 1; d < 256; d <<= 1){
    int add = (t >= d) ? sh[t - d] : 0;
    __syncthreads();
    sh[t] += add;
    __syncthreads();
  }
  if (t < NB) boff[t] = sh[t] - v;
  if (t == 255) row_ptr[NN] = sh[255];
}

__global__ void k_scatter(const int* __restrict__ deg, const int* __restrict__ boff,
                          int* __restrict__ row_ptr, float* __restrict__ dinv){
  __shared__ int sh[256];
  const int t = threadIdx.x;
  int i = blockIdx.x * 256 + t;
  int d = (i < NN) ? deg[i] : 0;
  sh[t] = d; __syncthreads();
  for (int dd = 1; dd < 256; dd <<= 1){
    int add = (t >= dd) ? sh[t - dd] : 0;
    __syncthreads();
    sh[t] += add;
    __syncthreads();
  }
  if (i < NN){
    row_ptr[i] = sh[t] - d + boff[blockIdx.x];
    dinv[i] = rsqrtf((float)d + 1.0f);   // +1 self-loop
  }
}

// ---- GEMM body: 128x128 tile, BK=64 (m97 recipe), XCD swizzle, LDS XOR-swz ----
// LDS per buffer: 2 k-planes of [128 rows][32 elems] bf16 (row pitch 64B).
// XOR swizzle addr ^= ((row&6)<<3) bytes kills the 8-way read conflict:
//   - gload_lds writes linearly -> pre-swizzle the GLOBAL source chunk
//     (rule #21): src col-chunk c' = (lane&3) ^ ((lr>>1)&3)
//   - CVT ds_write and all ds_reads apply the same XOR.
// 8 K-steps of 64 (vs 16 of 32): half the barriers, 32 MFMA/wave/step.
template<bool CVT>
static __device__ __forceinline__ void gemm_body(
    const int bx, const int t,
    const void* __restrict__ Av, const unsigned short* __restrict__ Bt,
    unsigned char* __restrict__ C,
    unsigned short (&As)[2][8192], unsigned short (&Bs)[2][8192]){
  const int wave = t >> 6, lane = t & 63;
  const int quad = lane >> 4, l15 = lane & 15;
  const int mw = (wave & 1) * 64;
  const int nw = (wave >> 1) * 64;
  const int g = bx >> 5, rem = bx & 31;
  const int rt = g * 8 + (rem & 7);
  const int rowBase = rt * 128;
  const int nBase = (rem >> 3) * 128;

  const int lr = lane >> 2;              // 16-row async chunks (4 lanes/row)
  const int lcs = (((lane & 3) ^ ((lr >> 1) & 3)) * 8);  // pre-swizzled src chunk
  const int lr8 = lane >> 3;             // 8-row f32 chunks (CVT path)
  const int lc8 = lane & 7;
  const unsigned short* Bg0 = Bt + (size_t)(nBase + wave * 32 + lr) * CH + lcs;
  const int boff = wave * 1024;          // 32 rows * 32 elems per wave per plane
  const float* X = (const float*)Av;
  const unsigned short* Ag0 = (const unsigned short*)Av;
  if (!CVT) Ag0 += (size_t)(rowBase + wave * 32 + lr) * CH + lcs;
  const int aoff = wave * 1024;

  int arow[4]; size_t asrc[4];
  int wswz = 0;
  if (CVT){
    #pragma unroll
    for (int q=0;q<4;q++){
      arow[q] = wave * 32 + q * 8 + lr8;               // local row in tile
      int gr = rowBase + arow[q];
      if (gr >= NN) gr = 0;                            // clamp: pad rows unread
      asrc[q] = (size_t)gr * CH + lc8 * 4;
    }
    wswz = (lc8 * 4) ^ ((lr8 & 6) << 2);               // swizzled write sub-chunk
  }
  const int rsw = (l15 & 6) << 2;                      // read-side XOR (shorts)

  f32x4 acc[4][4];
  #pragma unroll
  for (int i=0;i<4;i++)
    #pragma unroll
    for (int j=0;j<4;j++) acc[i][j] = 0;

  // ---- stage tile `it` (kb = it*64) into buffer buf ----
  // A (non-CVT) + B via gload_lds: 2 planes x 2 row-groups each.
  float4 apre[2][4];

  // prologue: tile 0
  if (CVT){
    #pragma unroll
    for (int p=0;p<2;p++)
      #pragma unroll
      for (int q=0;q<4;q++) apre[p][q] = *(const float4*)(X + asrc[q] + p*32);
    #pragma unroll
    for (int p=0;p<2;p++)
      #pragma unroll
      for (int q=0;q<4;q++){
        uint2 pk; pk.x = pack2(apre[p][q].x, apre[p][q].y);
        pk.y = pack2(apre[p][q].z, apre[p][q].w);
        *(uint2*)&As[0][p*4096 + arow[q]*32 + wswz] = pk;
      }
  } else {
    #pragma unroll
    for (int p=0;p<2;p++)
      #pragma unroll
      for (int gg=0;gg<2;gg++)
        __builtin_amdgcn_global_load_lds(
          (const __attribute__((address_space(1))) void*)(Ag0 + (size_t)gg*16*CH + p*32),
          (__attribute__((address_space(3))) void*)(&As[0][p*4096 + aoff + gg*512]), 16, 0, 0);
  }
  #pragma unroll
  for (int p=0;p<2;p++)
    #pragma unroll
    for (int gg=0;gg<2;gg++)
      __builtin_amdgcn_global_load_lds(
        (const __attribute__((address_space(1))) void*)(Bg0 + (size_t)gg*16*CH + p*32),
        (__attribute__((address_space(3))) void*)(&Bs[0][p*4096 + boff + gg*512]), 16, 0, 0);

  for (int it = 0; it < 8; it++){
    const int cur = it & 1, nxt = cur ^ 1;
    __syncthreads();   // tile `cur` fully staged; `nxt` free
    if (it < 7){
      const int kb = (it + 1) * 64;
      if (CVT){
        #pragma unroll
        for (int p=0;p<2;p++)
          #pragma unroll
          for (int q=0;q<4;q++) apre[p][q] = *(const float4*)(X + asrc[q] + kb + p*32);
      } else {
        #pragma unroll
        for (int p=0;p<2;p++)
          #pragma unroll
          for (int gg=0;gg<2;gg++)
            __builtin_amdgcn_global_load_lds(
              (const __attribute__((address_space(1))) void*)(Ag0 + (size_t)gg*16*CH + kb + p*32),
              (__attribute__((address_space(3))) void*)(&As[nxt][p*4096 + aoff + gg*512]), 16, 0, 0);
      }
      #pragma unroll
      for (int p=0;p<2;p++)
        #pragma unroll
        for (int gg=0;gg<2;gg++)
          __builtin_amdgcn_global_load_lds(
            (const __attribute__((address_space(1))) void*)(Bg0 + (size_t)gg*16*CH + kb + p*32),
            (__attribute__((address_space(3))) void*)(&Bs[nxt][p*4096 + boff + gg*512]), 16, 0, 0);
    }

    #pragma unroll
    for (int ks=0;ks<2;ks++){
      bf16x8 af[4], bfr[4];
      #pragma unroll
      for (int i=0;i<4;i++)
        af[i] = __builtin_bit_cast(bf16x8,
                *(const u16x8*)&As[cur][ks*4096 + (mw + i*16 + l15)*32 + (quad*8 ^ rsw)]);
      #pragma unroll
      for (int j=0;j<4;j++)
        bfr[j] = __builtin_bit_cast(bf16x8,
                *(const u16x8*)&Bs[cur][ks*4096 + (nw + j*16 + l15)*32 + (quad*8 ^ rsw)]);
      #pragma unroll
      for (int i=0;i<4;i++)
        #pragma unroll
        for (int j=0;j<4;j++)
          acc[i][j] = __builtin_amdgcn_mfma_f32_16x16x32_bf16(af[i], bfr[j], acc[i][j], 0, 0, 0);
    }

    if (CVT && it < 7){   // convert in the MFMA shadow, write into nxt
      #pragma unroll
      for (int p=0;p<2;p++)
        #pragma unroll
        for (int q=0;q<4;q++){
          uint2 pk; pk.x = pack2(apre[p][q].x, apre[p][q].y);
          pk.y = pack2(apre[p][q].z, apre[p][q].w);
          *(uint2*)&As[nxt][p*4096 + arow[q]*32 + wswz] = pk;
        }
    }
  }

  // permuted epilogue: lane packs its 4 j-values of one row -> 4B fp8 store
  #pragma unroll
  for (int i=0;i<4;i++){
    #pragma unroll
    for (int r=0;r<4;r++){
      int row = rowBase + mw + i*16 + quad*4 + r;
      int w0 = 0;
      w0 = __builtin_amdgcn_cvt_pk_fp8_f32(acc[i][0][r], acc[i][1][r], w0, false);
      w0 = __builtin_amdgcn_cvt_pk_fp8_f32(acc[i][2][r], acc[i][3][r], w0, true);
      *(unsigned*)(C + (size_t)row * CH + nBase + nw + l15*4) = (unsigned)w0;
    }
  }
}

// ---- gemm1: CVT (f32 x -> bf16 LDS), fp8 C ----
__launch_bounds__(256, 2)
__global__ void k_gemm1(const float* __restrict__ x, const unsigned short* __restrict__ W1t,
                        unsigned char* __restrict__ C){
  __shared__ __align__(16) unsigned short As[2][8192];
  __shared__ __align__(16) unsigned short Bs[2][8192];
  gemm_body<true>(blockIdx.x, threadIdx.x, x, W1t, C, As, Bs);
}

// ---- bucket: atomic-free CSR scatter (separate kernel) ----
__global__ void k_bucket(const int* __restrict__ ei, const int* __restrict__ row_ptr,
                         const int* __restrict__ rank, int* __restrict__ csr_src){
  int e2 = (blockIdx.x * 256 + threadIdx.x) * 2;
  if (e2 < NE){
    int2 src = *(const int2*)(ei + e2);
    int2 dst = *(const int2*)(ei + NE + e2);
    int2 rk  = *(const int2*)(rank + e2);
    csr_src[row_ptr[dst.x] + rk.x] = src.x;
    csr_src[row_ptr[dst.y] + rk.y] = src.y;
  }
}

// ---- gemm2: bf16 A (B0), LDS dbuf, fp8 C ----
__launch_bounds__(256, 2)
__global__ void k_gemm2(const unsigned short* __restrict__ A,
                        const unsigned short* __restrict__ Bt,
                        unsigned char* __restrict__ C){
  __shared__ __align__(16) unsigned short As[2][8192];
  __shared__ __align__(16) unsigned short Bs[2][8192];
  gemm_body<false>(blockIdx.x, threadIdx.x, A, Bt, C, As, Bs);
}

// ---- aggregation: relu(di*sum + di^2*self + b); optional fused head ----
// h table is FP8 e4m3 (512 B/row): halves the random-gather fetch volume.
template<bool HEAD>
__launch_bounds__(256)
__global__ void k_agg(const unsigned char* __restrict__ h, const int* __restrict__ row_ptr,
                      const int* __restrict__ csr_src, const float* __restrict__ dinv,
                      const float* __restrict__ bias, unsigned short* __restrict__ out,
                      const float* __restrict__ Wo, const float* __restrict__ bo,
                      float* __restrict__ logits){
  const int node = blockIdx.x * 4 + (threadIdx.x >> 6);
  const int lane = threadIdx.x & 63;
  float acc[8];
  #pragma unroll
  for (int k=0;k<8;k++) acc[k] = 0.f;
  const int rp = row_ptr[node], re = row_ptr[node + 1];
  for (int base = rp; base < re; base += 64){
    int cnt = re - base; if (cnt > 64) cnt = 64;
    int s = 0; float w = 0.f;
    if (base + lane < re){ s = csr_src[base + lane]; w = dinv[s]; }
    int j = 0;
    for (; j + 8 <= cnt; j += 8){
      int ss[8]; float ww[8]; uint2 hv[8];
      #pragma unroll
      for (int u=0;u<8;u++){
        ss[u] = __builtin_amdgcn_readlane(s, j + u);
        ww[u] = rdlane_f(w, j + u);
      }
      #pragma unroll
      for (int u=0;u<8;u++)
        hv[u] = *(const uint2*)(h + (size_t)ss[u] * CH + lane * 8);
      #pragma unroll
      for (int u=0;u<8;u++){
        f32x2 p0 = __builtin_amdgcn_cvt_pk_f32_fp8((int)hv[u].x, false);
        f32x2 p1 = __builtin_amdgcn_cvt_pk_f32_fp8((int)hv[u].x, true);
        f32x2 p2 = __builtin_amdgcn_cvt_pk_f32_fp8((int)hv[u].y, false);
        f32x2 p3 = __builtin_amdgcn_cvt_pk_f32_fp8((int)hv[u].y, true);
        acc[0] += ww[u] * p0.x; acc[1] += ww[u] * p0.y;
        acc[2] += ww[u] * p1.x; acc[3] += ww[u] * p1.y;
        acc[4] += ww[u] * p2.x; acc[5] += ww[u] * p2.y;
        acc[6] += ww[u] * p3.x; acc[7] += ww[u] * p3.y;
      }
    }
    for (; j < cnt; j++){
      int ss = __builtin_amdgcn_readlane(s, j);
      float ww = rdlane_f(w, j);
      uint2 hv = *(const uint2*)(h + (size_t)ss * CH + lane * 8);
      f32x2 p0 = __builtin_amdgcn_cvt_pk_f32_fp8((int)hv.x, false);
      f32x2 p1 = __builtin_amdgcn_cvt_pk_f32_fp8((int)hv.x, true);
      f32x2 p2 = __builtin_amdgcn_cvt_pk_f32_fp8((int)hv.y, false);
      f32x2 p3 = __builtin_amdgcn_cvt_pk_f32_fp8((int)hv.y, true);
      acc[0] += ww * p0.x; acc[1] += ww * p0.y;
      acc[2] += ww * p1.x; acc[3] += ww * p1.y;
      acc[4] += ww * p2.x; acc[5] += ww * p2.y;
      acc[6] += ww * p3.x; acc[7] += ww * p3.y;
    }
  }
  const float di = dinv[node];
  uint2 hsv = *(const uint2*)(h + (size_t)node * CH + lane * 8);
  f32x2 s0 = __builtin_amdgcn_cvt_pk_f32_fp8((int)hsv.x, false);
  f32x2 s1 = __builtin_amdgcn_cvt_pk_f32_fp8((int)hsv.x, true);
  f32x2 s2 = __builtin_amdgcn_cvt_pk_f32_fp8((int)hsv.y, false);
  f32x2 s3 = __builtin_amdgcn_cvt_pk_f32_fp8((int)hsv.y, true);
  float hsf[8] = {s0.x, s0.y, s1.x, s1.y, s2.x, s2.y, s3.x, s3.y};
  const float4* bp = (const float4*)(bias + lane * 8);
  float4 bv0 = bp[0], bv1 = bp[1];
  float bb[8] = {bv0.x,bv0.y,bv0.z,bv0.w,bv1.x,bv1.y,bv1.z,bv1.w};
  if (HEAD){
    const float4* wp = (const float4*)(Wo + lane * 8);
    float4 w0 = wp[0], w1 = wp[1];
    float wv[8] = {w0.x,w0.y,w0.z,w0.w,w1.x,w1.y,w1.z,w1.w};
    float v = 0.f;
    #pragma unroll
    for (int k=0;k<8;k++){
      float r = fmaxf(di * acc[k] + di * di * hsf[k] + bb[k], 0.f);
      v += r * wv[k];
    }
    #pragma unroll
    for (int off = 32; off > 0; off >>= 1) v += __shfl_down(v, off, 64);
    if (lane == 0) logits[node] = v + bo[0];
  } else {
    u16x8 o;
    #pragma unroll
    for (int k=0;k<8;k++){
      float r = fmaxf(di * acc[k] + di * di * hsf[k] + bb[k], 0.f);
      o[k] = f2b(r);
    }
    *(u16x8*)(out + (size_t)node * CH + lane * 8) = o;
  }
}

// ---- softmax: 49-block partial (m_b, s_b); final combine folded into write ----
__global__ void k_smpart(const float* __restrict__ logits, float* __restrict__ pm,
                         float* __restrict__ ps){
  __shared__ float shm[16], shs[16];
  const int t = threadIdx.x;
  const int i = blockIdx.x * 1024 + t;
  float v = (i < NN) ? logits[i] : -3.4e38f;
  float m = v;
  #pragma unroll
  for (int off = 32; off > 0; off >>= 1) m = fmaxf(m, __shfl_down(m, off, 64));
  if ((t & 63) == 0) shm[t >> 6] = m;
  __syncthreads();
  if (t < 64){
    float mm = (t < 16) ? shm[t] : -3.4e38f;
    #pragma unroll
    for (int off = 8; off > 0; off >>= 1) mm = fmaxf(mm, __shfl_down(mm, off, 64));
    if (t == 0) shm[0] = mm;
  }
  __syncthreads();
  const float bm = shm[0];
  float s = (i < NN) ? expf(v - bm) : 0.f;
  #pragma unroll
  for (int off = 32; off > 0; off >>= 1) s += __shfl_down(s, off, 64);
  if ((t & 63) == 0) shs[t >> 6] = s;
  __syncthreads();
  if (t < 64){
    float sss = (t < 16) ? shs[t] : 0.f;
    #pragma unroll
    for (int off = 8; off > 0; off >>= 1) sss += __shfl_down(sss, off, 64);
    if (t == 0){ pm[blockIdx.x] = bm; ps[blockIdx.x] = sss; }
  }
}

__global__ void k_smwrite(const float* __restrict__ logits, const float* __restrict__ pm,
                          const float* __restrict__ ps, float* __restrict__ out){
  __shared__ float shMS[2];
  const int t = threadIdx.x;
  if (t < 64){
    float m = (t < SMB) ? pm[t] : -3.4e38f;
    float M = m;
    #pragma unroll
    for (int off = 32; off > 0; off >>= 1) M = fmaxf(M, __shfl_down(M, off, 64));
    M = rdlane_f(M, 0);
    float s = (t < SMB) ? ps[t] * expf(m - M) : 0.f;
    #pragma unroll
    for (int off = 32; off > 0; off >>= 1) s += __shfl_down(s, off, 64);
    if (t == 0){ shMS[0] = M; shMS[1] = s; }
  }
  __syncthreads();
  int i = blockIdx.x * blockDim.x + t;
  if (i < NN) out[i] = expf(logits[i] - shMS[0]) / shMS[1];
}

extern "C" void kernel_launch(void* const* d_in, const int* in_sizes, int n_in,
                              void* d_out, int out_size, void* d_ws, size_t ws_size,
                              hipStream_t stream){
  const float* x  = (const float*)d_in[0];
  const int*   ei = (const int*)d_in[1];
  const float* W1 = (const float*)d_in[2];
  const float* b1 = (const float*)d_in[3];
  const float* W2 = (const float*)d_in[4];
  const float* b2 = (const float*)d_in[5];
  const float* Wo = (const float*)d_in[6];
  const float* bo = (const float*)d_in[7];
  float* out = (float*)d_out;

  char* ws = (char*)d_ws;
  size_t off = 0;
  auto alloc = [&](size_t bytes) -> void* {
    void* p = ws + off;
    off = (off + bytes + 255) & ~(size_t)255;
    return p;
  };
  unsigned short* B0  = (unsigned short*)alloc((size_t)NP * CH * 2);  // bf16 (gemm2 A input)
  unsigned char*  B1  = (unsigned char*)alloc((size_t)NP * CH);      // fp8 gather table
  unsigned short* W1t = (unsigned short*)alloc((size_t)CH * CH * 2);
  unsigned short* W2t = (unsigned short*)alloc((size_t)CH * CH * 2);
  int*   deg     = (int*)alloc((size_t)NN * 4);
  float* dinv    = (float*)alloc((size_t)NN * 4);
  int*   row_ptr = (int*)alloc((size_t)(NN + 1) * 4);
  int*   rank    = (int*)alloc((size_t)NE * 4);
  int*   csr     = (int*)alloc((size_t)NE * 4);
  float* logits  = (float*)alloc((size_t)NN * 4);
  int*   bsum    = (int*)alloc((size_t)NB * 4);
  int*   boff    = (int*)alloc((size_t)NB * 4);
  float* pm      = (float*)alloc((size_t)SMB * 4);
  float* ps      = (float*)alloc((size_t)SMB * 4);
  float* b1p     = (float*)alloc((size_t)CH * 4);
  float* b2p     = (float*)alloc((size_t)CH * 4);
  float* Wop     = (float*)alloc((size_t)CH * 4);

  hipMemsetAsync(deg, 0, (size_t)NN * 4, stream);
  k_prep<<<PB_TRANS + PB_DEG + PB_PERM, 256, 0, stream>>>(
      W1, W2, W1t, W2t, ei, deg, rank, b1, b2, Wo, b1p, b2p, Wop);
  k_blocksum<<<NB, 256, 0, stream>>>(deg, bsum);
  k_scanoff<<<1, 256, 0, stream>>>(bsum, boff, row_ptr);
  k_scatter<<<NB, 256, 0, stream>>>(deg, boff, row_ptr, dinv);

  k_bucket<<<BKB, 256, 0, stream>>>(ei, row_ptr, rank, csr);
  k_gemm1<<<GB1, 256, 0, stream>>>(x, W1t, B1);
  k_agg<false><<<NN / 4, 256, 0, stream>>>(B1, row_ptr, csr, dinv, b1p, B0,
                                           Wop, bo, logits);
  k_gemm2<<<GB1, 256, 0, stream>>>(B0, W2t, B1);
  k_agg<true><<<NN / 4, 256, 0, stream>>>(B1, row_ptr, csr, dinv, b2p, B0,
                                          Wop, bo, logits);

  k_smpart<<<SMB, 1024, 0, stream>>>(logits, pm, ps);
  k_smwrite<<<NB, 256, 0, stream>>>(logits, pm, ps, out);
}

// Round 9
// 422.866 us; speedup vs baseline: 1.0778x; 1.0205x over previous
//
#include <hip/hip_runtime.h>

#define NN 50000
#define NP 50176      // 392 row-tiles of 128; 392 % 8 == 0 for XCD grouping
#define NE 800000
#define CH 512
#define NB 196        // ceil(50000/256) scan blocks
#define PB_TRANS 2048 // 2 * CH*CH/256
#define PB_DEG 782    // ceil(NE/4/256)
#define PB_PERM 6     // 3*512/256 permuted-vector blocks
#define SMB 49        // softmax partial blocks (49*1024 >= 50000)
#define GB1 (4 * (NP / 128))          // 1568 gemm blocks (128x128 tiles)
#define BKB ((NE / 2 + 255) / 256)    // 1563 bucket blocks

typedef __bf16 bf16x8 __attribute__((ext_vector_type(8)));
typedef float f32x4 __attribute__((ext_vector_type(4)));
typedef float f32x2 __attribute__((ext_vector_type(2)));
typedef unsigned short u16x8 __attribute__((ext_vector_type(8)));

static __device__ __forceinline__ unsigned short f2b(float f){
  unsigned u = __builtin_bit_cast(unsigned, f);
  u = (u + 0x7fffu + ((u >> 16) & 1u)) >> 16;   // RNE f32 -> bf16
  return (unsigned short)u;
}
static __device__ __forceinline__ float b2f(unsigned short h){
  unsigned u = ((unsigned)h) << 16;
  return __builtin_bit_cast(float, u);
}
static __device__ __forceinline__ float rdlane_f(float v, int l){
  return __builtin_bit_cast(float, __builtin_amdgcn_readlane(__builtin_bit_cast(int, v), l));
}
// pack two f32 -> two bf16 (round-half-up) in one dword: 2 adds + 1 v_perm
static __device__ __forceinline__ unsigned pack2(float f0, float f1){
  unsigned u0 = __builtin_bit_cast(unsigned, f0) + 0x8000u;
  unsigned u1 = __builtin_bit_cast(unsigned, f1) + 0x8000u;
  return __builtin_amdgcn_perm(u1, u0, 0x07060302u);  // [u1.hi16 | u0.hi16]
}
// physical column p -> logical channel (epilogue permutation, within 64-blocks)
// epilogue stores logical (j*16 + l15) at physical (l15*4 + j), j<4, l15<16
static __device__ __forceinline__ int lam(int p){
  return (p & ~63) | (((p & 3) << 4) + ((p & 63) >> 2));
}

// ---- prep: W1t | W2t (k-permuted) | deg hist (+edge rank) | permuted vecs ----
__global__ void k_prep(const float* __restrict__ W1, const float* __restrict__ W2,
                       unsigned short* __restrict__ W1t, unsigned short* __restrict__ W2t,
                       const int* __restrict__ ei, int* __restrict__ deg,
                       int* __restrict__ rank,
                       const float* __restrict__ b1, const float* __restrict__ b2,
                       const float* __restrict__ Wo, float* __restrict__ b1p,
                       float* __restrict__ b2p, float* __restrict__ Wop){
  const int b = blockIdx.x, t = threadIdx.x;
  if (b < PB_TRANS){
    int idx = (b & 1023) * 256 + t;
    int n = idx >> 9, p = idx & (CH - 1);
    if (b < 1024)
      W1t[n * CH + p] = f2b(W1[p * CH + n]);            // logical k
    else
      W2t[n * CH + p] = f2b(W2[lam(p) * CH + n]);       // k permuted to match B0 layout
  } else if (b < PB_TRANS + PB_DEG){
    int e4 = ((b - PB_TRANS) * 256 + t) * 4;
    if (e4 < NE){
      int4 d = *(const int4*)(ei + NE + e4);
      int4 r;
      r.x = atomicAdd(&deg[d.x], 1);
      r.y = atomicAdd(&deg[d.y], 1);
      r.z = atomicAdd(&deg[d.z], 1);
      r.w = atomicAdd(&deg[d.w], 1);
      *(int4*)(rank + e4) = r;   // within-node rank; makes bucket atomic-free
    }
  } else {
    int idx = (b - PB_TRANS - PB_DEG) * 256 + t;  // [0,1536)
    int which = idx >> 9, p = idx & (CH - 1);
    int l = lam(p);
    if (which == 0) b1p[p] = b1[l];
    else if (which == 1) b2p[p] = b2[l];
    else Wop[p] = Wo[l];
  }
}

// ---- block sums of deg (scan folded into k_scatter; k_scanoff removed) ----
__global__ void k_blocksum(const int* __restrict__ deg, int* __restrict__ bsum){
  __shared__ int sh[4];
  const int t = threadIdx.x;
  int i = blockIdx.x * 256 + t;
  int v = (i < NN) ? deg[i] : 0;
  #pragma unroll
  for (int off = 32; off > 0; off >>= 1) v += __shfl_down(v, off, 64);
  if ((t & 63) == 0) sh[t >> 6] = v;
  __syncthreads();
  if (t == 0) bsum[blockIdx.x] = sh[0] + sh[1] + sh[2] + sh[3];
}

// scatter with in-kernel scan of bsum: each block redundantly scans the 196
// block sums (L2-hot, ~1 us) to derive its exclusive offset -> one less launch
__global__ void k_scatter(const int* __restrict__ deg, const int* __restrict__ bsum,
                          int* __restrict__ row_ptr, float* __restrict__ dinv){
  __shared__ int sh[256];
  __shared__ int base;
  const int t = threadIdx.x;
  int bv = (t < NB) ? bsum[t] : 0;
  sh[t] = bv; __syncthreads();
  for (int d = 1; d < 256; d <<= 1){
    int add = (t >= d) ? sh[t - d] : 0;
    __syncthreads();
    sh[t] += add;
    __syncthreads();
  }
  if (t == (int)blockIdx.x) base = sh[t] - bv;       // exclusive prefix of this block
  if (blockIdx.x == 0 && t == 255) row_ptr[NN] = sh[255];
  __syncthreads();
  const int boff0 = base;
  int i = blockIdx.x * 256 + t;
  int d0 = (i < NN) ? deg[i] : 0;
  sh[t] = d0; __syncthreads();
  for (int dd = 1; dd < 256; dd <<= 1){
    int add = (t >= dd) ? sh[t - dd] : 0;
    __syncthreads();
    sh[t] += add;
    __syncthreads();
  }
  if (i < NN){
    row_ptr[i] = sh[t] - d0 + boff0;
    dinv[i] = rsqrtf((float)d0 + 1.0f);   // +1 self-loop
  }
}

// ---- GEMM body: 128x128 tile, BK=64, XCD swizzle, LDS XOR-swz (R7, verified) ----
// LDS per buffer: 2 k-planes of [128 rows][32 elems] bf16 (row pitch 64B).
// XOR swizzle addr ^= ((row&6)<<3) bytes kills the 8-way read conflict:
//   - gload_lds writes linearly -> pre-swizzle the GLOBAL source chunk
//   - CVT ds_write and all ds_reads apply the same XOR.
// Structure ceiling ~80us measured (R4-R7 invariant): K=512 gives only 8
// latency-exposed K-steps/block; accepted for this session.
template<bool CVT>
static __device__ __forceinline__ void gemm_body(
    const int bx, const int t,
    const void* __restrict__ Av, const unsigned short* __restrict__ Bt,
    unsigned char* __restrict__ C,
    unsigned short (&As)[2][8192], unsigned short (&Bs)[2][8192]){
  const int wave = t >> 6, lane = t & 63;
  const int quad = lane >> 4, l15 = lane & 15;
  const int mw = (wave & 1) * 64;
  const int nw = (wave >> 1) * 64;
  const int g = bx >> 5, rem = bx & 31;
  const int rt = g * 8 + (rem & 7);
  const int rowBase = rt * 128;
  const int nBase = (rem >> 3) * 128;

  const int lr = lane >> 2;              // 16-row async chunks (4 lanes/row)
  const int lcs = (((lane & 3) ^ ((lr >> 1) & 3)) * 8);  // pre-swizzled src chunk
  const int lr8 = lane >> 3;             // 8-row f32 chunks (CVT path)
  const int lc8 = lane & 7;
  const unsigned short* Bg0 = Bt + (size_t)(nBase + wave * 32 + lr) * CH + lcs;
  const int boff = wave * 1024;          // 32 rows * 32 elems per wave per plane
  const float* X = (const float*)Av;
  const unsigned short* Ag0 = (const unsigned short*)Av;
  if (!CVT) Ag0 += (size_t)(rowBase + wave * 32 + lr) * CH + lcs;
  const int aoff = wave * 1024;

  int arow[4]; size_t asrc[4];
  int wswz = 0;
  if (CVT){
    #pragma unroll
    for (int q=0;q<4;q++){
      arow[q] = wave * 32 + q * 8 + lr8;               // local row in tile
      int gr = rowBase + arow[q];
      if (gr >= NN) gr = 0;                            // clamp: pad rows unread
      asrc[q] = (size_t)gr * CH + lc8 * 4;
    }
    wswz = (lc8 * 4) ^ ((lr8 & 6) << 2);               // swizzled write sub-chunk
  }
  const int rsw = (l15 & 6) << 2;                      // read-side XOR (shorts)

  f32x4 acc[4][4];
  #pragma unroll
  for (int i=0;i<4;i++)
    #pragma unroll
    for (int j=0;j<4;j++) acc[i][j] = 0;

  float4 apre[2][4];

  // prologue: tile 0
  if (CVT){
    #pragma unroll
    for (int p=0;p<2;p++)
      #pragma unroll
      for (int q=0;q<4;q++) apre[p][q] = *(const float4*)(X + asrc[q] + p*32);
    #pragma unroll
    for (int p=0;p<2;p++)
      #pragma unroll
      for (int q=0;q<4;q++){
        uint2 pk; pk.x = pack2(apre[p][q].x, apre[p][q].y);
        pk.y = pack2(apre[p][q].z, apre[p][q].w);
        *(uint2*)&As[0][p*4096 + arow[q]*32 + wswz] = pk;
      }
  } else {
    #pragma unroll
    for (int p=0;p<2;p++)
      #pragma unroll
      for (int gg=0;gg<2;gg++)
        __builtin_amdgcn_global_load_lds(
          (const __attribute__((address_space(1))) void*)(Ag0 + (size_t)gg*16*CH + p*32),
          (__attribute__((address_space(3))) void*)(&As[0][p*4096 + aoff + gg*512]), 16, 0, 0);
  }
  #pragma unroll
  for (int p=0;p<2;p++)
    #pragma unroll
    for (int gg=0;gg<2;gg++)
      __builtin_amdgcn_global_load_lds(
        (const __attribute__((address_space(1))) void*)(Bg0 + (size_t)gg*16*CH + p*32),
        (__attribute__((address_space(3))) void*)(&Bs[0][p*4096 + boff + gg*512]), 16, 0, 0);

  for (int it = 0; it < 8; it++){
    const int cur = it & 1, nxt = cur ^ 1;
    __syncthreads();   // tile `cur` fully staged; `nxt` free
    if (it < 7){
      const int kb = (it + 1) * 64;
      if (CVT){
        #pragma unroll
        for (int p=0;p<2;p++)
          #pragma unroll
          for (int q=0;q<4;q++) apre[p][q] = *(const float4*)(X + asrc[q] + kb + p*32);
      } else {
        #pragma unroll
        for (int p=0;p<2;p++)
          #pragma unroll
          for (int gg=0;gg<2;gg++)
            __builtin_amdgcn_global_load_lds(
              (const __attribute__((address_space(1))) void*)(Ag0 + (size_t)gg*16*CH + kb + p*32),
              (__attribute__((address_space(3))) void*)(&As[nxt][p*4096 + aoff + gg*512]), 16, 0, 0);
      }
      #pragma unroll
      for (int p=0;p<2;p++)
        #pragma unroll
        for (int gg=0;gg<2;gg++)
          __builtin_amdgcn_global_load_lds(
            (const __attribute__((address_space(1))) void*)(Bg0 + (size_t)gg*16*CH + kb + p*32),
            (__attribute__((address_space(3))) void*)(&Bs[nxt][p*4096 + boff + gg*512]), 16, 0, 0);
    }

    #pragma unroll
    for (int ks=0;ks<2;ks++){
      bf16x8 af[4], bfr[4];
      #pragma unroll
      for (int i=0;i<4;i++)
        af[i] = __builtin_bit_cast(bf16x8,
                *(const u16x8*)&As[cur][ks*4096 + (mw + i*16 + l15)*32 + (quad*8 ^ rsw)]);
      #pragma unroll
      for (int j=0;j<4;j++)
        bfr[j] = __builtin_bit_cast(bf16x8,
                *(const u16x8*)&Bs[cur][ks*4096 + (nw + j*16 + l15)*32 + (quad*8 ^ rsw)]);
      #pragma unroll
      for (int i=0;i<4;i++)
        #pragma unroll
        for (int j=0;j<4;j++)
          acc[i][j] = __builtin_amdgcn_mfma_f32_16x16x32_bf16(af[i], bfr[j], acc[i][j], 0, 0, 0);
    }

    if (CVT && it < 7){   // convert in the MFMA shadow, write into nxt
      #pragma unroll
      for (int p=0;p<2;p++)
        #pragma unroll
        for (int q=0;q<4;q++){
          uint2 pk; pk.x = pack2(apre[p][q].x, apre[p][q].y);
          pk.y = pack2(apre[p][q].z, apre[p][q].w);
          *(uint2*)&As[nxt][p*4096 + arow[q]*32 + wswz] = pk;
        }
    }
  }

  // permuted epilogue: lane packs its 4 j-values of one row -> 4B fp8 store
  #pragma unroll
  for (int i=0;i<4;i++){
    #pragma unroll
    for (int r=0;r<4;r++){
      int row = rowBase + mw + i*16 + quad*4 + r;
      int w0 = 0;
      w0 = __builtin_amdgcn_cvt_pk_fp8_f32(acc[i][0][r], acc[i][1][r], w0, false);
      w0 = __builtin_amdgcn_cvt_pk_fp8_f32(acc[i][2][r], acc[i][3][r], w0, true);
      *(unsigned*)(C + (size_t)row * CH + nBase + nw + l15*4) = (unsigned)w0;
    }
  }
}

// ---- fused: gemm1 (CVT) || bucket scatter. R2/R4 data: co-run wins ~10-15us
// (bucket rides gemm1's ~80%-idle memory pipes; fusion 98 vs 83+20+gap split).
__launch_bounds__(256, 2)
__global__ void k_g1bkt(const float* __restrict__ x, const unsigned short* __restrict__ W1t,
                        unsigned char* __restrict__ C,
                        const int* __restrict__ ei, const int* __restrict__ row_ptr,
                        const int* __restrict__ rank, int* __restrict__ csr_src){
  __shared__ __align__(16) unsigned short As[2][8192];
  __shared__ __align__(16) unsigned short Bs[2][8192];
  const int b = blockIdx.x;
  if (b < GB1){
    gemm_body<true>(b, threadIdx.x, x, W1t, C, As, Bs);
  } else {
    int e2 = ((b - GB1) * 256 + threadIdx.x) * 2;
    if (e2 < NE){
      int2 src = *(const int2*)(ei + e2);
      int2 dst = *(const int2*)(ei + NE + e2);
      int2 rk  = *(const int2*)(rank + e2);
      csr_src[row_ptr[dst.x] + rk.x] = src.x;
      csr_src[row_ptr[dst.y] + rk.y] = src.y;
    }
  }
}

// ---- gemm2: bf16 A (B0), LDS dbuf, fp8 C ----
__launch_bounds__(256, 2)
__global__ void k_gemm2(const unsigned short* __restrict__ A,
                        const unsigned short* __restrict__ Bt,
                        unsigned char* __restrict__ C){
  __shared__ __align__(16) unsigned short As[2][8192];
  __shared__ __align__(16) unsigned short Bs[2][8192];
  gemm_body<false>(blockIdx.x, threadIdx.x, A, Bt, C, As, Bs);
}

// ---- aggregation: relu(di*sum + di^2*self + b); optional fused head ----
// h table is FP8 e4m3 (512 B/row): halves the random-gather fetch volume.
template<bool HEAD>
__launch_bounds__(256)
__global__ void k_agg(const unsigned char* __restrict__ h, const int* __restrict__ row_ptr,
                      const int* __restrict__ csr_src, const float* __restrict__ dinv,
                      const float* __restrict__ bias, unsigned short* __restrict__ out,
                      const float* __restrict__ Wo, const float* __restrict__ bo,
                      float* __restrict__ logits){
  const int node = blockIdx.x * 4 + (threadIdx.x >> 6);
  const int lane = threadIdx.x & 63;
  float acc[8];
  #pragma unroll
  for (int k=0;k<8;k++) acc[k] = 0.f;
  const int rp = row_ptr[node], re = row_ptr[node + 1];
  for (int base = rp; base < re; base += 64){
    int cnt = re - base; if (cnt > 64) cnt = 64;
    int s = 0; float w = 0.f;
    if (base + lane < re){ s = csr_src[base + lane]; w = dinv[s]; }
    int j = 0;
    for (; j + 8 <= cnt; j += 8){
      int ss[8]; float ww[8]; uint2 hv[8];
      #pragma unroll
      for (int u=0;u<8;u++){
        ss[u] = __builtin_amdgcn_readlane(s, j + u);
        ww[u] = rdlane_f(w, j + u);
      }
      #pragma unroll
      for (int u=0;u<8;u++)
        hv[u] = *(const uint2*)(h + (size_t)ss[u] * CH + lane * 8);
      #pragma unroll
      for (int u=0;u<8;u++){
        f32x2 p0 = __builtin_amdgcn_cvt_pk_f32_fp8((int)hv[u].x, false);
        f32x2 p1 = __builtin_amdgcn_cvt_pk_f32_fp8((int)hv[u].x, true);
        f32x2 p2 = __builtin_amdgcn_cvt_pk_f32_fp8((int)hv[u].y, false);
        f32x2 p3 = __builtin_amdgcn_cvt_pk_f32_fp8((int)hv[u].y, true);
        acc[0] += ww[u] * p0.x; acc[1] += ww[u] * p0.y;
        acc[2] += ww[u] * p1.x; acc[3] += ww[u] * p1.y;
        acc[4] += ww[u] * p2.x; acc[5] += ww[u] * p2.y;
        acc[6] += ww[u] * p3.x; acc[7] += ww[u] * p3.y;
      }
    }
    for (; j < cnt; j++){
      int ss = __builtin_amdgcn_readlane(s, j);
      float ww = rdlane_f(w, j);
      uint2 hv = *(const uint2*)(h + (size_t)ss * CH + lane * 8);
      f32x2 p0 = __builtin_amdgcn_cvt_pk_f32_fp8((int)hv.x, false);
      f32x2 p1 = __builtin_amdgcn_cvt_pk_f32_fp8((int)hv.x, true);
      f32x2 p2 = __builtin_amdgcn_cvt_pk_f32_fp8((int)hv.y, false);
      f32x2 p3 = __builtin_amdgcn_cvt_pk_f32_fp8((int)hv.y, true);
      acc[0] += ww * p0.x; acc[1] += ww * p0.y;
      acc[2] += ww * p1.x; acc[3] += ww * p1.y;
      acc[4] += ww * p2.x; acc[5] += ww * p2.y;
      acc[6] += ww * p3.x; acc[7] += ww * p3.y;
    }
  }
  const float di = dinv[node];
  uint2 hsv = *(const uint2*)(h + (size_t)node * CH + lane * 8);
  f32x2 s0 = __builtin_amdgcn_cvt_pk_f32_fp8((int)hsv.x, false);
  f32x2 s1 = __builtin_amdgcn_cvt_pk_f32_fp8((int)hsv.x, true);
  f32x2 s2 = __builtin_amdgcn_cvt_pk_f32_fp8((int)hsv.y, false);
  f32x2 s3 = __builtin_amdgcn_cvt_pk_f32_fp8((int)hsv.y, true);
  float hsf[8] = {s0.x, s0.y, s1.x, s1.y, s2.x, s2.y, s3.x, s3.y};
  const float4* bp = (const float4*)(bias + lane * 8);
  float4 bv0 = bp[0], bv1 = bp[1];
  float bb[8] = {bv0.x,bv0.y,bv0.z,bv0.w,bv1.x,bv1.y,bv1.z,bv1.w};
  if (HEAD){
    const float4* wp = (const float4*)(Wo + lane * 8);
    float4 w0 = wp[0], w1 = wp[1];
    float wv[8] = {w0.x,w0.y,w0.z,w0.w,w1.x,w1.y,w1.z,w1.w};
    float v = 0.f;
    #pragma unroll
    for (int k=0;k<8;k++){
      float r = fmaxf(di * acc[k] + di * di * hsf[k] + bb[k], 0.f);
      v += r * wv[k];
    }
    #pragma unroll
    for (int off = 32; off > 0; off >>= 1) v += __shfl_down(v, off, 64);
    if (lane == 0) logits[node] = v + bo[0];
  } else {
    u16x8 o;
    #pragma unroll
    for (int k=0;k<8;k++){
      float r = fmaxf(di * acc[k] + di * di * hsf[k] + bb[k], 0.f);
      o[k] = f2b(r);
    }
    *(u16x8*)(out + (size_t)node * CH + lane * 8) = o;
  }
}

// ---- softmax: 49-block partial (m_b, s_b); final combine folded into write ----
__global__ void k_smpart(const float* __restrict__ logits, float* __restrict__ pm,
                         float* __restrict__ ps){
  __shared__ float shm[16], shs[16];
  const int t = threadIdx.x;
  const int i = blockIdx.x * 1024 + t;
  float v = (i < NN) ? logits[i] : -3.4e38f;
  float m = v;
  #pragma unroll
  for (int off = 32; off > 0; off >>= 1) m = fmaxf(m, __shfl_down(m, off, 64));
  if ((t & 63) == 0) shm[t >> 6] = m;
  __syncthreads();
  if (t < 64){
    float mm = (t < 16) ? shm[t] : -3.4e38f;
    #pragma unroll
    for (int off = 8; off > 0; off >>= 1) mm = fmaxf(mm, __shfl_down(mm, off, 64));
    if (t == 0) shm[0] = mm;
  }
  __syncthreads();
  const float bm = shm[0];
  float s = (i < NN) ? expf(v - bm) : 0.f;
  #pragma unroll
  for (int off = 32; off > 0; off >>= 1) s += __shfl_down(s, off, 64);
  if ((t & 63) == 0) shs[t >> 6] = s;
  __syncthreads();
  if (t < 64){
    float sss = (t < 16) ? shs[t] : 0.f;
    #pragma unroll
    for (int off = 8; off > 0; off >>= 1) sss += __shfl_down(sss, off, 64);
    if (t == 0){ pm[blockIdx.x] = bm; ps[blockIdx.x] = sss; }
  }
}

__global__ void k_smwrite(const float* __restrict__ logits, const float* __restrict__ pm,
                          const float* __restrict__ ps, float* __restrict__ out){
  __shared__ float shMS[2];
  const int t = threadIdx.x;
  if (t < 64){
    float m = (t < SMB) ? pm[t] : -3.4e38f;
    float M = m;
    #pragma unroll
    for (int off = 32; off > 0; off >>= 1) M = fmaxf(M, __shfl_down(M, off, 64));
    M = rdlane_f(M, 0);
    float s = (t < SMB) ? ps[t] * expf(m - M) : 0.f;
    #pragma unroll
    for (int off = 32; off > 0; off >>= 1) s += __shfl_down(s, off, 64);
    if (t == 0){ shMS[0] = M; shMS[1] = s; }
  }
  __syncthreads();
  int i = blockIdx.x * blockDim.x + t;
  if (i < NN) out[i] = expf(logits[i] - shMS[0]) / shMS[1];
}

extern "C" void kernel_launch(void* const* d_in, const int* in_sizes, int n_in,
                              void* d_out, int out_size, void* d_ws, size_t ws_size,
                              hipStream_t stream){
  const float* x  = (const float*)d_in[0];
  const int*   ei = (const int*)d_in[1];
  const float* W1 = (const float*)d_in[2];
  const float* b1 = (const float*)d_in[3];
  const float* W2 = (const float*)d_in[4];
  const float* b2 = (const float*)d_in[5];
  const float* Wo = (const float*)d_in[6];
  const float* bo = (const float*)d_in[7];
  float* out = (float*)d_out;

  char* ws = (char*)d_ws;
  size_t off = 0;
  auto alloc = [&](size_t bytes) -> void* {
    void* p = ws + off;
    off = (off + bytes + 255) & ~(size_t)255;
    return p;
  };
  unsigned short* B0  = (unsigned short*)alloc((size_t)NP * CH * 2);  // bf16 (gemm2 A input)
  unsigned char*  B1  = (unsigned char*)alloc((size_t)NP * CH);      // fp8 gather table
  unsigned short* W1t = (unsigned short*)alloc((size_t)CH * CH * 2);
  unsigned short* W2t = (unsigned short*)alloc((size_t)CH * CH * 2);
  int*   deg     = (int*)alloc((size_t)NN * 4);
  float* dinv    = (float*)alloc((size_t)NN * 4);
  int*   row_ptr = (int*)alloc((size_t)(NN + 1) * 4);
  int*   rank    = (int*)alloc((size_t)NE * 4);
  int*   csr     = (int*)alloc((size_t)NE * 4);
  float* logits  = (float*)alloc((size_t)NN * 4);
  int*   bsum    = (int*)alloc((size_t)NB * 4);
  float* pm      = (float*)alloc((size_t)SMB * 4);
  float* ps      = (float*)alloc((size_t)SMB * 4);
  float* b1p     = (float*)alloc((size_t)CH * 4);
  float* b2p     = (float*)alloc((size_t)CH * 4);
  float* Wop     = (float*)alloc((size_t)CH * 4);

  hipMemsetAsync(deg, 0, (size_t)NN * 4, stream);
  k_prep<<<PB_TRANS + PB_DEG + PB_PERM, 256, 0, stream>>>(
      W1, W2, W1t, W2t, ei, deg, rank, b1, b2, Wo, b1p, b2p, Wop);
  k_blocksum<<<NB, 256, 0, stream>>>(deg, bsum);
  k_scatter<<<NB, 256, 0, stream>>>(deg, bsum, row_ptr, dinv);

  k_g1bkt<<<GB1 + BKB, 256, 0, stream>>>(x, W1t, B1, ei, row_ptr, rank, csr);
  k_agg<false><<<NN / 4, 256, 0, stream>>>(B1, row_ptr, csr, dinv, b1p, B0,
                                           Wop, bo, logits);
  k_gemm2<<<GB1, 256, 0, stream>>>(B0, W2t, B1);
  k_agg<true><<<NN / 4, 256, 0, stream>>>(B1, row_ptr, csr, dinv, b2p, B0,
                                          Wop, bo, logits);

  k_smpart<<<SMB, 1024, 0, stream>>>(logits, pm, ps);
  k_smwrite<<<NB, 256, 0, stream>>>(logits, pm, ps, out);
}